// Round 18
// baseline (5627.932 us; speedup 1.0000x reference)
//
#include <hip/hip_runtime.h>
#include <hip/hip_bf16.h>
#include <math.h>

// ---------------------------------------------------------------------------
// HybridGemmaDiT forward.  B=64, S=256 (16x16), D=768, L=8, NH=4, HD=192.
// R18: R17 (passed, 5.47ms) + gemm_big retrial as the single variable.
//      R16's NaN is now attributed to the unsigned-underflow band-limit
//      (fixed in R17); gemm_big (256Mx128N 8-wave) was never tested alone.
//      qkv/mlpo -> gemm_big; gemm_mfma removed.
// ---------------------------------------------------------------------------

#define DEV static __device__ __forceinline__

typedef float    f32x4 __attribute__((ext_vector_type(4)));
typedef short    s16x8 __attribute__((ext_vector_type(8)));
typedef unsigned short u16x8 __attribute__((ext_vector_type(8)));
typedef unsigned short u16x4 __attribute__((ext_vector_type(4)));

constexpr int Bb = 64, Ss = 256, Dd = 768, Ll = 8, NHh = 4, HDd = 192;
constexpr int M_TOK = Bb * Ss;                 // 16384
constexpr float EPS_RMS = 1.1920929e-07f;
constexpr float ATT_SCALE = 0.07216878364870322f;  // 1/sqrt(192)
constexpr size_t ARENA_K = (size_t)Bb * NHh * Ss * HDd;   // 12,582,912 elems

// ---- workspace layout (BYTES) ---------------------------------------------
constexpr size_t B_SPINS  = 0;
constexpr size_t B_SCALEF = 2048;
constexpr size_t B_QT     = 5120;                        // 8*192*192 f32
constexpr size_t B_COS    = B_QT + 1179648;
constexpr size_t B_SIN    = B_COS + 196608;
constexpr size_t B_G      = B_SIN + 196608;              // 8*96*96 f32
constexpr size_t B_T      = B_G + 294912;
constexpr size_t B_AWY    = B_T + 294912;                // 8*96*192 f32
constexpr size_t B_ROWLAM = B_AWY + 589824;              // 16384 f32
constexpr size_t B_X      = B_ROWLAM + 65536;            // 16384*768 f32
constexpr size_t B_H      = B_X + 50331648;              // bf16
constexpr size_t B_PROJ   = B_H + 25165824;              // bf16 (unused)
constexpr size_t B_WEFFT  = B_PROJ + 25165824;           // 8*2304*768 bf16
constexpr size_t B_OUTWT  = B_WEFFT + 28311552;
constexpr size_t B_GATEWT = B_OUTWT + 9437184;           // unused
constexpr size_t B_MLPGT  = B_GATEWT + 9437184;          // 8*6144*768 bf16
constexpr size_t B_MLPOT  = B_MLPGT + 75497472;          // 8*768*3072 bf16
constexpr size_t B_W2T    = B_MLPOT + 37748736;          // 8*768*768 bf16
constexpr size_t B_ARENA  = B_W2T + 9437184;             // q,k,v^T,attn bf16 | hidden

DEV float sigmoidf_(float x) { return 1.0f / (1.0f + expf(-x)); }
DEV float geluf_(float g)    { return 0.5f * g * (1.0f + erff(g * 0.7071067811865476f)); }
DEV unsigned short f2bf(float f) {
    union { float f; unsigned u; } a; a.f = f;
    unsigned u = a.u + 0x7fffu + ((a.u >> 16) & 1u);
    return (unsigned short)(u >> 16);
}
DEV float b2f(unsigned short u) {
    union { unsigned u; float f; } a; a.u = ((unsigned)u) << 16; return a.f;
}
DEV void gload16(const void* g, void* l) {
    __builtin_amdgcn_global_load_lds((const __attribute__((address_space(1))) void*)g,
                                     (__attribute__((address_space(3))) void*)l, 16, 0, 0);
}

// 2D-chunked XCD-aware swizzle (bijective when gy%8==0 and gx%CX==0)
DEV void xcd_chunk(int gx, int gy, int CX, int& bx, int& by) {
    int id = by * gx + bx;
    int c = id & 7;
    int s = id >> 3;
    int CY = gy >> 3;
    int subsz = CY * CX;
    int bxc = s / subsz;
    int r = s - bxc * subsz;
    int byl = r / CX;
    by = c * CY + byl;
    bx = bxc * CX + (r - byl * CX);
}

// ---------------------------------------------------------------------------
__global__ void spins_kernel(const float* __restrict__ logsnr, float* __restrict__ spins) {
    int b = threadIdx.x;
    if (b < 64) {
        float v = logsnr[b];
#pragma unroll
        for (int j = 0; j < 4; ++j) {
            float ang = v * (float)(1 << j);
            spins[b * 8 + j]     = sinf(ang);
            spins[b * 8 + 4 + j] = cosf(ang);
        }
    }
}

__global__ void rope_table_kernel(float* __restrict__ cosb, float* __restrict__ sinb) {
    int s = blockIdx.x, j = threadIdx.x;
    int y = s >> 4, x = s & 15;
    int base = j % 96;
    float coord, invf;
    if (base < 48) { invf = expf(-(float)base * (2.0f / 96.0f) * 9.210340371976184f); coord = (float)y; }
    else { int i = base - 48; invf = expf(-(float)i * (2.0f / 96.0f) * 9.210340371976184f); coord = (float)x; }
    float f = coord * invf, sv, cv;
    sincosf(f, &sv, &cv);
    cosb[s * 192 + j] = cv;
    sinb[s * 192 + j] = sv;
}

// ---- WY householder: qt = Q^T = I - Y^T T Y -------------------------------
__global__ __launch_bounds__(256) void hh_gram_kernel(const float* __restrict__ hh_vs,
                                                      float* __restrict__ Gm) {
    __shared__ float Y[96][192];
    int l = blockIdx.x, t = threadIdx.x;
    const float4* src = (const float4*)(hh_vs + (size_t)l * 96 * 192);
    for (int i = t; i < 4608; i += 256) ((float4*)&Y[0][0])[i] = src[i];
    __syncthreads();
    for (int e = t; e < 9216; e += 256) {
        int i = e / 96, j = e - (e / 96) * 96;
        float acc = 0.f;
        for (int d = 0; d < 48; ++d) {
            float4 a = *(const float4*)&Y[i][d * 4];
            float4 b = *(const float4*)&Y[j][d * 4];
            acc += a.x * b.x + a.y * b.y + a.z * b.z + a.w * b.w;
        }
        Gm[(size_t)l * 9216 + e] = acc;
    }
}

__global__ __launch_bounds__(128) void hh_t_kernel(const float* __restrict__ Gm,
                                                   float* __restrict__ Tm) {
    __shared__ float G[96][96];
    __shared__ float Tt[96][96];
    int l = blockIdx.x, t = threadIdx.x;
    const float* Gl = Gm + (size_t)l * 9216;
    for (int i = t; i < 9216; i += 128) { ((float*)G)[i] = Gl[i]; ((float*)Tt)[i] = 0.f; }
    __syncthreads();
    if (t < 96) Tt[t][t] = 2.0f / (G[t][t] + 1e-8f);
    __syncthreads();
    for (int j = 1; j < 96; ++j) {
        if (t < 96) {
            float cj = 2.0f / (G[j][j] + 1e-8f);
            float dot = 0.f;
            for (int p = 0; p < j; ++p) dot += Tt[p][t] * G[p][j];
            if (t < j) Tt[j][t] = -cj * dot;
        }
        __syncthreads();
    }
    for (int i = t; i < 9216; i += 128) Tm[(size_t)l * 9216 + i] = ((float*)Tt)[i];
}

__global__ __launch_bounds__(256) void hh_a_kernel(const float* __restrict__ Tm,
                                                   const float* __restrict__ hh_vs,
                                                   float* __restrict__ Am) {
    __shared__ float T[96][96];
    __shared__ float Y[96][192];
    int l = blockIdx.x, t = threadIdx.x;
    const float* Tl = Tm + (size_t)l * 9216;
    const float4* src = (const float4*)(hh_vs + (size_t)l * 96 * 192);
    for (int i = t; i < 9216; i += 256) ((float*)T)[i] = Tl[i];
    for (int i = t; i < 4608; i += 256) ((float4*)&Y[0][0])[i] = src[i];
    __syncthreads();
    for (int idx = t; idx < 4608; idx += 256) {
        int i = idx / 48, e0 = (idx % 48) * 4;
        float4 acc = {0.f, 0.f, 0.f, 0.f};
        for (int j = i; j < 96; ++j) {
            float tv = T[j][i];
            float4 y = *(const float4*)&Y[j][e0];
            acc.x += tv * y.x; acc.y += tv * y.y; acc.z += tv * y.z; acc.w += tv * y.w;
        }
        *(float4*)(Am + (size_t)l * 96 * 192 + (size_t)i * 192 + e0) = acc;
    }
}

__global__ __launch_bounds__(256) void hh_p_kernel(const float* __restrict__ hh_vs,
                                                   const float* __restrict__ Am,
                                                   float* __restrict__ qt) {
    __shared__ float Y[96][192];
    __shared__ float A[96][192];
    int l = blockIdx.x, t = threadIdx.x;
    const float4* ys = (const float4*)(hh_vs + (size_t)l * 96 * 192);
    const float4* as = (const float4*)(Am + (size_t)l * 96 * 192);
    for (int i = t; i < 4608; i += 256) { ((float4*)&Y[0][0])[i] = ys[i]; ((float4*)&A[0][0])[i] = as[i]; }
    __syncthreads();
    for (int idx = t; idx < 9216; idx += 256) {
        int d = idx / 48, e0 = (idx % 48) * 4;
        float4 acc = {0.f, 0.f, 0.f, 0.f};
        for (int i = 0; i < 96; ++i) {
            float yv = Y[i][d];
            float4 a = *(const float4*)&A[i][e0];
            acc.x += yv * a.x; acc.y += yv * a.y; acc.z += yv * a.z; acc.w += yv * a.w;
        }
        acc.x = (d == e0 + 0 ? 1.f : 0.f) - acc.x;
        acc.y = (d == e0 + 1 ? 1.f : 0.f) - acc.y;
        acc.z = (d == e0 + 2 ? 1.f : 0.f) - acc.z;
        acc.w = (d == e0 + 3 ? 1.f : 0.f) - acc.w;
        *(float4*)(qt + (size_t)l * 192 * 192 + (size_t)d * 192 + e0) = acc;
    }
}

// fold + transpose + bf16 in one: weff_t[n][k] = sum_d qkv_w[k][d] qt[d][n]
__global__ __launch_bounds__(256) void fold_bf16t(const float* __restrict__ qkv_w,
                                                  const float* __restrict__ qt,
                                                  unsigned short* __restrict__ weff_t) {
    int z = blockIdx.z;
    int l = z >> 3, which = (z >> 2) & 1, head = z & 3;
    const float* A  = qkv_w + (size_t)l * 768 * 2304 + (size_t)which * 768 + head * 192;
    const float* Bq = qt + (size_t)l * 192 * 192;
    unsigned short* C = weff_t + (size_t)l * 2304 * 768 + ((size_t)which * 768 + head * 192) * 768;
    int row0 = blockIdx.y * 64, col0 = blockIdx.x * 64;
    __shared__ float As[64][65];
    __shared__ float Bs[64][65];
    int tid = threadIdx.x, tx = tid & 15, ty = tid >> 4;
    float acc[4][4] = {};
    for (int k0 = 0; k0 < 192; k0 += 64) {
        for (int i = tid; i < 1024; i += 256) {
            int r = i >> 4, kq = i & 15;
            float4 va = *(const float4*)(A + (size_t)(row0 + r) * 2304 + k0 + kq * 4);
            As[kq * 4 + 0][r] = va.x; As[kq * 4 + 1][r] = va.y; As[kq * 4 + 2][r] = va.z; As[kq * 4 + 3][r] = va.w;
        }
        for (int i = tid; i < 1024; i += 256) {
            int r = i >> 4, nq = i & 15;
            float4 vb = *(const float4*)(Bq + (size_t)(k0 + r) * 192 + col0 + nq * 4);
            Bs[r][nq * 4 + 0] = vb.x; Bs[r][nq * 4 + 1] = vb.y; Bs[r][nq * 4 + 2] = vb.z; Bs[r][nq * 4 + 3] = vb.w;
        }
        __syncthreads();
        for (int k = 0; k < 64; ++k) {
            float a[4], bb[4];
#pragma unroll
            for (int m = 0; m < 4; ++m) a[m] = As[k][ty * 4 + m];
#pragma unroll
            for (int n = 0; n < 4; ++n) bb[n] = Bs[k][tx * 4 + n];
#pragma unroll
            for (int m = 0; m < 4; ++m)
#pragma unroll
                for (int n = 0; n < 4; ++n) acc[m][n] = fmaf(a[m], bb[n], acc[m][n]);
        }
        __syncthreads();
    }
    float (*Tr)[65] = (float(*)[65])As;
#pragma unroll
    for (int m = 0; m < 4; ++m)
#pragma unroll
        for (int n = 0; n < 4; ++n) Tr[tx * 4 + n][ty * 4 + m] = acc[m][n];
    __syncthreads();
    int nl = tid >> 2, kc = (tid & 3) * 16;
#pragma unroll
    for (int q4 = 0; q4 < 4; ++q4) {
        u16x4 o;
#pragma unroll
        for (int ii = 0; ii < 4; ++ii) o[ii] = f2bf(Tr[nl][kc + q4 * 4 + ii]);
        *(u16x4*)(C + (size_t)(col0 + nl) * 768 + row0 + kc + q4 * 4) = o;
    }
}

// W2t[n][k] = sum_d out_w[k][d] * gate_w[d][n]  (fp32 in, bf16 [n][k] out)
__global__ __launch_bounds__(256) void w2_bf16t(const float* __restrict__ ow,
                                                const float* __restrict__ gw,
                                                unsigned short* __restrict__ w2t) {
    int l = blockIdx.z;
    const float* A = ow + (size_t)l * 768 * 768;
    const float* B = gw + (size_t)l * 768 * 768;
    unsigned short* C = w2t + (size_t)l * 768 * 768;
    int row0 = blockIdx.y * 64, col0 = blockIdx.x * 64;
    __shared__ float As[64][65];
    __shared__ float Bs[64][65];
    int tid = threadIdx.x, tx = tid & 15, ty = tid >> 4;
    float acc[4][4] = {};
    for (int k0 = 0; k0 < 768; k0 += 64) {
        for (int i = tid; i < 1024; i += 256) {
            int r = i >> 4, kq = i & 15;
            float4 va = *(const float4*)(A + (size_t)(row0 + r) * 768 + k0 + kq * 4);
            As[kq * 4 + 0][r] = va.x; As[kq * 4 + 1][r] = va.y; As[kq * 4 + 2][r] = va.z; As[kq * 4 + 3][r] = va.w;
        }
        for (int i = tid; i < 1024; i += 256) {
            int r = i >> 4, nq = i & 15;
            float4 vb = *(const float4*)(B + (size_t)(k0 + r) * 768 + col0 + nq * 4);
            Bs[r][nq * 4 + 0] = vb.x; Bs[r][nq * 4 + 1] = vb.y; Bs[r][nq * 4 + 2] = vb.z; Bs[r][nq * 4 + 3] = vb.w;
        }
        __syncthreads();
        for (int k = 0; k < 64; ++k) {
            float a[4], bb[4];
#pragma unroll
            for (int m = 0; m < 4; ++m) a[m] = As[k][ty * 4 + m];
#pragma unroll
            for (int n = 0; n < 4; ++n) bb[n] = Bs[k][tx * 4 + n];
#pragma unroll
            for (int m = 0; m < 4; ++m)
#pragma unroll
                for (int n = 0; n < 4; ++n) acc[m][n] = fmaf(a[m], bb[n], acc[m][n]);
        }
        __syncthreads();
    }
    float (*Tr)[65] = (float(*)[65])As;
#pragma unroll
    for (int m = 0; m < 4; ++m)
#pragma unroll
        for (int n = 0; n < 4; ++n) Tr[tx * 4 + n][ty * 4 + m] = acc[m][n];
    __syncthreads();
    int nl = tid >> 2, kc = (tid & 3) * 16;
#pragma unroll
    for (int q4 = 0; q4 < 4; ++q4) {
        u16x4 o;
#pragma unroll
        for (int ii = 0; ii < 4; ++ii) o[ii] = f2bf(Tr[nl][kc + q4 * 4 + ii]);
        *(u16x4*)(C + (size_t)(col0 + nl) * 768 + row0 + kc + q4 * 4) = o;
    }
}

// strided fp32 [K][N] -> bf16 [N][K]
__global__ __launch_bounds__(256) void transpose_bf16_kernel(const float* __restrict__ W,
                                                             int ldw, size_t zsrc,
                                                             unsigned short* __restrict__ Wt,
                                                             int ldwt, size_t zdst) {
    __shared__ float t[32][33];
    const float* Wz = W + (size_t)blockIdx.z * zsrc;
    unsigned short* Wtz = Wt + (size_t)blockIdx.z * zdst;
    int k0 = blockIdx.y * 32, n0 = blockIdx.x * 32;
    int tid = threadIdx.x;
    int tr = tid >> 3, tc = tid & 7;
    float4 v = *(const float4*)(Wz + (size_t)(k0 + tr) * ldw + n0 + tc * 4);
    t[tr][tc * 4 + 0] = v.x; t[tr][tc * 4 + 1] = v.y; t[tr][tc * 4 + 2] = v.z; t[tr][tc * 4 + 3] = v.w;
    __syncthreads();
    u16x4 o;
    o[0] = f2bf(t[tc * 4 + 0][tr]); o[1] = f2bf(t[tc * 4 + 1][tr]);
    o[2] = f2bf(t[tc * 4 + 2][tr]); o[3] = f2bf(t[tc * 4 + 3][tr]);
    *(u16x4*)(Wtz + (size_t)(n0 + tr) * ldwt + k0 + tc * 4) = o;
}

__global__ __launch_bounds__(256) void patch_embed_kernel(const float* __restrict__ z_t,
                                                          const float* __restrict__ spins,
                                                          const float* __restrict__ patch_w,
                                                          const float* __restrict__ patch_b,
                                                          float* __restrict__ x) {
    int bs = blockIdx.x;
    int b = bs >> 8, s = bs & 255;
    int gy = s >> 4, gx = s & 15;
    __shared__ float in20[20];
    int t = threadIdx.x;
    if (t < 12) {
        int c = t >> 2, py = (t >> 1) & 1, px = t & 1;
        in20[t] = z_t[(((size_t)b * 3 + c) * 32 + (2 * gy + py)) * 32 + (2 * gx + px)];
    } else if (t < 20) {
        in20[t] = spins[b * 8 + (t - 12)];
    }
    __syncthreads();
    for (int d = t; d < 768; d += 256) {
        float acc = patch_b[d];
#pragma unroll
        for (int i = 0; i < 20; ++i) acc += in20[i] * patch_w[i * 768 + d];
        x[(size_t)bs * 768 + d] = acc;
    }
}

// wave-per-row rmsnorm: 4 rows/block, lane owns 12 contiguous d
__global__ __launch_bounds__(256) void rmsnorm_kernel(const float* __restrict__ x,
                                                      unsigned short* __restrict__ h) {
    int wave = threadIdx.x >> 6, lane = threadIdx.x & 63;
    int row = blockIdx.x * 4 + wave;
    const float* xr = x + (size_t)row * 768 + lane * 12;
    float4 a = *(const float4*)(xr);
    float4 b = *(const float4*)(xr + 4);
    float4 c = *(const float4*)(xr + 8);
    float ss = a.x*a.x + a.y*a.y + a.z*a.z + a.w*a.w
             + b.x*b.x + b.y*b.y + b.z*b.z + b.w*b.w
             + c.x*c.x + c.y*c.y + c.z*c.z + c.w*c.w;
#pragma unroll
    for (int msk = 1; msk < 64; msk <<= 1) ss += __shfl_xor(ss, msk);
    float sc = 1.0f / sqrtf(ss / 768.0f + EPS_RMS);
    unsigned short* hr = h + (size_t)row * 768 + lane * 12;
    u16x4 o0, o1, o2;
    o0[0]=f2bf(a.x*sc); o0[1]=f2bf(a.y*sc); o0[2]=f2bf(a.z*sc); o0[3]=f2bf(a.w*sc);
    o1[0]=f2bf(b.x*sc); o1[1]=f2bf(b.y*sc); o1[2]=f2bf(b.z*sc); o1[3]=f2bf(b.w*sc);
    o2[0]=f2bf(c.x*sc); o2[1]=f2bf(c.y*sc); o2[2]=f2bf(c.z*sc); o2[3]=f2bf(c.w*sc);
    *(u16x4*)(hr) = o0; *(u16x4*)(hr + 4) = o1; *(u16x4*)(hr + 8) = o2;
}

// ---- big single-B GEMM: 256Mx128N, 8 waves, single-buffer -----------------
// 24 chunks/k-tile (16 A + 8 B), 3 per wave.  EPI: 1=qkv scatter  4=x+=v
template <int EPI>
__global__ __launch_bounds__(512) void gemm_big(const unsigned short* __restrict__ A, int lda,
                                                const unsigned short* __restrict__ Bt, int ldb,
                                                unsigned short* __restrict__ Cb, int ldc, int K,
                                                const float* __restrict__ bias,
                                                float* __restrict__ Xf,
                                                int CX) {
    __shared__ unsigned short As[8192];   // 256 rows x 32 k
    __shared__ unsigned short Bs[4096];   // 128 rows x 32 k
    int tid = threadIdx.x;
    int wave = tid >> 6, lane = tid & 63;
    int bx = blockIdx.x, by = blockIdx.y;
    xcd_chunk(gridDim.x, gridDim.y, CX, bx, by);
    int row0 = by * 256, col0 = bx * 128;
    int wm = wave >> 1, wn = wave & 1;
    f32x4 acc[4][4] = {};

    int srow = lane >> 2;
    int ksw = (((lane & 3) ^ (srow & 3)) * 8);
    int lrow = lane & 15;
    int csw = (((lane >> 4) ^ (lane & 3)) * 8);

    for (int k0 = 0; k0 < K; k0 += 32) {
#pragma unroll
        for (int it = 0; it < 3; ++it) {
            int chunk = wave * 3 + it;              // 0..23
            if (chunk < 16) {
                int r = chunk * 16 + srow;
                gload16(A + (size_t)(row0 + r) * lda + k0 + ksw, &As[chunk * 512]);
            } else {
                int r = (chunk - 16) * 16 + srow;
                gload16(Bt + (size_t)(col0 + r) * ldb + k0 + ksw, &Bs[(chunk - 16) * 512]);
            }
        }
        __syncthreads();
        s16x8 af[4], bf[4];
#pragma unroll
        for (int m = 0; m < 4; ++m)
            af[m] = *(const s16x8*)&As[(wm * 64 + m * 16 + lrow) * 32 + csw];
#pragma unroll
        for (int n = 0; n < 4; ++n)
            bf[n] = *(const s16x8*)&Bs[(wn * 64 + n * 16 + lrow) * 32 + csw];
#pragma unroll
        for (int m = 0; m < 4; ++m)
#pragma unroll
            for (int n = 0; n < 4; ++n)
                acc[m][n] = __builtin_amdgcn_mfma_f32_16x16x32_bf16(af[m], bf[n], acc[m][n], 0, 0, 0);
        __syncthreads();
    }

    int lquad = lane >> 4;
#pragma unroll
    for (int m = 0; m < 4; ++m) {
#pragma unroll
        for (int n = 0; n < 4; ++n) {
#pragma unroll
            for (int r = 0; r < 4; ++r) {
                int i = row0 + wm * 64 + m * 16 + lquad * 4 + r;
                int j = col0 + wn * 64 + n * 16 + lrow;
                float v = acc[m][n][r];
                if (bias) v += bias[j];
                if constexpr (EPI == 1) {
                    int which = j / 768;
                    int rem = j - which * 768;
                    int head = rem / 192;
                    int hd = rem - head * 192;
                    int b = i >> 8, s = i & 255;
                    if (which == 2) {   // V transposed: [bh][d][s]
                        Cb[2 * ARENA_K + (((size_t)(b * 4 + head)) * 192 + hd) * 256 + s] = f2bf(v);
                    } else {
                        Cb[(size_t)which * ARENA_K + (((size_t)(b * 4 + head)) * 256 + s) * 192 + hd] = f2bf(v);
                    }
                } else if constexpr (EPI == 4) {
                    Xf[(size_t)i * ldc + j] += v;
                }
            }
        }
    }
}

// ---- fused MLP-in GEMM: 256Mx64N, 8 waves, single-buffer ------------------
__global__ __launch_bounds__(512) void gemm_mlp_fused(const unsigned short* __restrict__ A,
                                                      const unsigned short* __restrict__ Bt,
                                                      unsigned short* __restrict__ Hid,
                                                      const float* __restrict__ bias,
                                                      int CX) {
    __shared__ unsigned short As[8192];
    __shared__ unsigned short Bs[8192];
    int tid = threadIdx.x;
    int wave = tid >> 6, lane = tid & 63;
    int bx = blockIdx.x, by = blockIdx.y;
    xcd_chunk(gridDim.x, gridDim.y, CX, bx, by);
    int row0 = by * 256, col0 = bx * 64;
    int wm = wave >> 1, wn = wave & 1;
    f32x4 accg[4][2] = {};
    f32x4 accv[4][2] = {};

    int srow = lane >> 2;
    int ksw = (((lane & 3) ^ (srow & 3)) * 8);
    int lrow = lane & 15;
    int csw = (((lane >> 4) ^ (lane & 3)) * 8);

    const unsigned short* Bg = Bt + (size_t)col0 * 768;
    const unsigned short* Bv = Bt + (size_t)(3072 + col0) * 768;

    for (int k0 = 0; k0 < 768; k0 += 32) {
#pragma unroll
        for (int it = 0; it < 2; ++it) {
            int chunk = it * 8 + wave;
            int r = chunk * 16 + srow;
            gload16(A + (size_t)(row0 + r) * 768 + k0 + ksw, &As[chunk * 512]);
        }
        {
            int half = wave >> 2;
            int chunk = wave & 3;
            int r = chunk * 16 + srow;
            const unsigned short* Bh = half ? Bv : Bg;
            gload16(Bh + (size_t)r * 768 + k0 + ksw, &Bs[half * 4096 + chunk * 512]);
        }
        __syncthreads();
        s16x8 af[4], bgf[2], bvf[2];
#pragma unroll
        for (int m = 0; m < 4; ++m)
            af[m] = *(const s16x8*)&As[(wm * 64 + m * 16 + lrow) * 32 + csw];
#pragma unroll
        for (int n = 0; n < 2; ++n) {
            bgf[n] = *(const s16x8*)&Bs[(wn * 32 + n * 16 + lrow) * 32 + csw];
            bvf[n] = *(const s16x8*)&Bs[4096 + (wn * 32 + n * 16 + lrow) * 32 + csw];
        }
#pragma unroll
        for (int m = 0; m < 4; ++m)
#pragma unroll
            for (int n = 0; n < 2; ++n) {
                accg[m][n] = __builtin_amdgcn_mfma_f32_16x16x32_bf16(af[m], bgf[n], accg[m][n], 0, 0, 0);
                accv[m][n] = __builtin_amdgcn_mfma_f32_16x16x32_bf16(af[m], bvf[n], accv[m][n], 0, 0, 0);
            }
        __syncthreads();
    }

    int lquad = lane >> 4;
#pragma unroll
    for (int m = 0; m < 4; ++m) {
#pragma unroll
        for (int n = 0; n < 2; ++n) {
#pragma unroll
            for (int r = 0; r < 4; ++r) {
                int i = row0 + wm * 64 + m * 16 + lquad * 4 + r;
                int j = col0 + wn * 32 + n * 16 + lrow;
                float g = accg[m][n][r] + bias[j];
                float v = accv[m][n][r] + bias[3072 + j];
                Hid[(size_t)i * 3072 + j] = f2bf(v * geluf_(g));
            }
        }
    }
}

// ---- fused proj+gate GEMM: 256Mx64N, 8 waves ------------------------------
__global__ __launch_bounds__(512) void gemm_projgate(const unsigned short* __restrict__ A,
                                                     const unsigned short* __restrict__ B1t,
                                                     const unsigned short* __restrict__ B2t,
                                                     const float* __restrict__ gate_b,
                                                     float* __restrict__ Xf,
                                                     int CX) {
    __shared__ unsigned short As[8192];
    __shared__ unsigned short Bs[8192];
    int tid = threadIdx.x;
    int wave = tid >> 6, lane = tid & 63;
    int bx = blockIdx.x, by = blockIdx.y;
    xcd_chunk(gridDim.x, gridDim.y, CX, bx, by);
    int row0 = by * 256, col0 = bx * 64;
    int wm = wave >> 1, wn = wave & 1;
    f32x4 accp[4][2] = {};
    f32x4 accg[4][2] = {};

    int srow = lane >> 2;
    int ksw = (((lane & 3) ^ (srow & 3)) * 8);
    int lrow = lane & 15;
    int csw = (((lane >> 4) ^ (lane & 3)) * 8);

    const unsigned short* B1 = B1t + (size_t)col0 * 768;
    const unsigned short* B2 = B2t + (size_t)col0 * 768;

    for (int k0 = 0; k0 < 768; k0 += 32) {
#pragma unroll
        for (int it = 0; it < 2; ++it) {
            int chunk = it * 8 + wave;
            int r = chunk * 16 + srow;
            gload16(A + (size_t)(row0 + r) * 768 + k0 + ksw, &As[chunk * 512]);
        }
        {
            int half = wave >> 2;
            int chunk = wave & 3;
            int r = chunk * 16 + srow;
            const unsigned short* Bh = half ? B2 : B1;
            gload16(Bh + (size_t)r * 768 + k0 + ksw, &Bs[half * 4096 + chunk * 512]);
        }
        __syncthreads();
        s16x8 af[4], b1f[2], b2f_[2];
#pragma unroll
        for (int m = 0; m < 4; ++m)
            af[m] = *(const s16x8*)&As[(wm * 64 + m * 16 + lrow) * 32 + csw];
#pragma unroll
        for (int n = 0; n < 2; ++n) {
            b1f[n]  = *(const s16x8*)&Bs[(wn * 32 + n * 16 + lrow) * 32 + csw];
            b2f_[n] = *(const s16x8*)&Bs[4096 + (wn * 32 + n * 16 + lrow) * 32 + csw];
        }
#pragma unroll
        for (int m = 0; m < 4; ++m)
#pragma unroll
            for (int n = 0; n < 2; ++n) {
                accp[m][n] = __builtin_amdgcn_mfma_f32_16x16x32_bf16(af[m], b1f[n],  accp[m][n], 0, 0, 0);
                accg[m][n] = __builtin_amdgcn_mfma_f32_16x16x32_bf16(af[m], b2f_[n], accg[m][n], 0, 0, 0);
            }
        __syncthreads();
    }

    int lquad = lane >> 4;
#pragma unroll
    for (int m = 0; m < 4; ++m) {
#pragma unroll
        for (int n = 0; n < 2; ++n) {
#pragma unroll
            for (int r = 0; r < 4; ++r) {
                int i = row0 + wm * 64 + m * 16 + lquad * 4 + r;
                int j = col0 + wn * 32 + n * 16 + lrow;
                float p1 = accp[m][n][r];
                float p2 = accg[m][n][r] + gate_b[j];
                Xf[(size_t)i * 768 + j] += p1 * sigmoidf_(p2);
            }
        }
    }
}

// ---- MFMA attention: fused RoPE + exact local skip + band-limited staging -
__global__ __launch_bounds__(512) void attn_mfma_kernel(const unsigned short* __restrict__ qb_,
                                                        const unsigned short* __restrict__ kb_,
                                                        const unsigned short* __restrict__ vtb_,
                                                        unsigned short* __restrict__ attnb,
                                                        const float* __restrict__ cosb,
                                                        const float* __restrict__ sinb,
                                                        int glob) {
    __shared__ unsigned short Klds[256 * 200];
    __shared__ unsigned short Vlds[192 * 72];
    __shared__ unsigned short Plds[8 * 16 * 72];
    int b = blockIdx.z, hh = blockIdx.y;
    int tid = threadIdx.x;
    int wave = tid >> 6, lane = tid & 63;
    int bxs = (int)blockIdx.x;
    int q0 = bxs * 128 + wave * 16;
    int yq = q0 >> 4;
    size_t bh = (size_t)(b * 4 + hh);
    const unsigned short* qb  = qb_  + bh * 49152;
    const unsigned short* kb  = kb_  + bh * 49152;
    const unsigned short* vtb = vtb_ + bh * 49152;

    // K rows needed by this block: y in [bxs*8-2, bxs*8+9] on local layers
    int rlo, rhi;
    if (glob) { rlo = 0; rhi = 256; }
    else {
        int lo = (bxs * 8 - 2) * 16;  if (lo < 0) lo = 0;
        int hi = (bxs * 8 + 10) * 16; if (hi > 256) hi = 256;
        rlo = lo; rhi = hi;
    }

    for (int c = tid; c < 6144; c += 512) {
        int r = c / 24, col = c - (c / 24) * 24;
        if (r < rlo || r >= rhi) continue;
        int j0 = col * 8;
        int jp = j0 < 96 ? j0 + 96 : j0 - 96;
        float sgn = j0 < 96 ? -1.f : 1.f;
        u16x8 a = *(const u16x8*)(kb + (size_t)r * 192 + j0);
        u16x8 p = *(const u16x8*)(kb + (size_t)r * 192 + jp);
        const float* cr = cosb + r * 192 + j0;
        const float* sr = sinb + r * 192 + j0;
        u16x8 o;
#pragma unroll
        for (int i = 0; i < 8; ++i)
            o[i] = f2bf(b2f(a[i]) * cr[i] + sgn * b2f(p[i]) * sr[i]);
        *(u16x8*)&Klds[r * 200 + j0] = o;
    }
    __syncthreads();

    s16x8 qf[6];
    {
        int sq = q0 + (lane & 15);
        const unsigned short* qrow = qb + (size_t)sq * 192;
        const float* cr = cosb + sq * 192;
        const float* sr = sinb + sq * 192;
#pragma unroll
        for (int kk = 0; kk < 6; ++kk) {
            int ck = kk * 32 + (lane >> 4) * 8;
            int cp = ck < 96 ? ck + 96 : ck - 96;
            float sgn = ck < 96 ? -1.f : 1.f;
            u16x8 a = *(const u16x8*)(qrow + ck);
            u16x8 p = *(const u16x8*)(qrow + cp);
            s16x8 o;
#pragma unroll
            for (int i = 0; i < 8; ++i)
                o[i] = (short)f2bf(b2f(a[i]) * cr[ck + i] + sgn * b2f(p[i]) * sr[ck + i]);
            qf[kk] = o;
        }
    }

    f32x4 sc[16];
#pragma unroll
    for (int n = 0; n < 16; ++n) sc[n] = (f32x4){0.f, 0.f, 0.f, 0.f};
#pragma unroll
    for (int kk = 0; kk < 6; ++kk) {
#pragma unroll
        for (int n = 0; n < 16; ++n) {
            if (glob || (n >= yq - 2 && n <= yq + 2)) {
                s16x8 bf = *(const s16x8*)&Klds[(n * 16 + (lane & 15)) * 200 + kk * 32 + (lane >> 4) * 8];
                sc[n] = __builtin_amdgcn_mfma_f32_16x16x32_bf16(qf[kk], bf, sc[n], 0, 0, 0);
            }
        }
    }

    int lq = (lane >> 4) * 4;
#pragma unroll
    for (int n = 0; n < 16; ++n) {
        int sk = n * 16 + (lane & 15);
        int yk = sk >> 4, xk = sk & 15;
#pragma unroll
        for (int r = 0; r < 4; ++r) {
            int sq = q0 + lq + r;
            int dy = (sq >> 4) - yk, dx = (sq & 15) - xk;
            bool keep = glob || (dy * dy + dx * dx) < 7;
            sc[n][r] = keep ? sc[n][r] * ATT_SCALE : -1e30f;
        }
    }
    float rmax[4], rsum[4];
#pragma unroll
    for (int r = 0; r < 4; ++r) {
        float m = sc[0][r];
#pragma unroll
        for (int n = 1; n < 16; ++n) m = fmaxf(m, sc[n][r]);
#pragma unroll
        for (int msk = 1; msk < 16; msk <<= 1) m = fmaxf(m, __shfl_xor(m, msk));
        rmax[r] = m;
    }
#pragma unroll
    for (int r = 0; r < 4; ++r) {
        float e = 0.f;
#pragma unroll
        for (int n = 0; n < 16; ++n) { float p = expf(sc[n][r] - rmax[r]); sc[n][r] = p; e += p; }
#pragma unroll
        for (int msk = 1; msk < 16; msk <<= 1) e += __shfl_xor(e, msk);
        rsum[r] = 1.0f / e;
    }

    f32x4 o[12];
#pragma unroll
    for (int n = 0; n < 12; ++n) o[n] = (f32x4){0.f, 0.f, 0.f, 0.f};
    unsigned short* Pw = &Plds[wave * 1152];
    int ylo = bxs * 8 - 2, yhi = bxs * 8 + 9;
    for (int kt = 0; kt < 4; ++kt) {
        if (!glob && !((4 * kt + 3 >= ylo) && (4 * kt <= yhi))) continue;
#pragma unroll
        for (int nn = 0; nn < 4; ++nn) {
#pragma unroll
            for (int r = 0; r < 4; ++r)
                Pw[(lq + r) * 72 + nn * 16 + (lane & 15)] = f2bf(sc[kt * 4 + nn][r] * rsum[r]);
        }
        __syncthreads();
        for (int c = tid; c < 1536; c += 512) {
            int r = c >> 3, col = c & 7;
            *(u16x8*)&Vlds[r * 72 + col * 8] = *(const u16x8*)(vtb + (size_t)r * 256 + kt * 64 + col * 8);
        }
        __syncthreads();
        s16x8 af[2];
#pragma unroll
        for (int kk2 = 0; kk2 < 2; ++kk2)
            af[kk2] = *(const s16x8*)&Pw[(lane & 15) * 72 + kk2 * 32 + (lane >> 4) * 8];
#pragma unroll
        for (int n = 0; n < 12; ++n) {
#pragma unroll
            for (int kk2 = 0; kk2 < 2; ++kk2) {
                s16x8 bf = *(const s16x8*)&Vlds[(n * 16 + (lane & 15)) * 72 + kk2 * 32 + (lane >> 4) * 8];
                o[n] = __builtin_amdgcn_mfma_f32_16x16x32_bf16(af[kk2], bf, o[n], 0, 0, 0);
            }
        }
    }
#pragma unroll
    for (int n = 0; n < 12; ++n) {
        int d = n * 16 + (lane & 15);
#pragma unroll
        for (int r = 0; r < 4; ++r) {
            int sq = q0 + lq + r;
            attnb[((size_t)(b * 256 + sq)) * 768 + hh * 192 + d] = f2bf(o[n][r]);
        }
    }
}

__global__ __launch_bounds__(768) void scalef_kernel(const float* __restrict__ spins,
                                                     const float* __restrict__ sd1_w,
                                                     const float* __restrict__ sd1_b,
                                                     const float* __restrict__ sd2_w,
                                                     const float* __restrict__ sd2_b,
                                                     float* __restrict__ scalef) {
    int b = blockIdx.x, t = threadIdx.x;
    __shared__ float hid[768];
    __shared__ float sp[8];
    if (t < 8) sp[t] = spins[b * 8 + t];
    __syncthreads();
    float acc = sd1_b[t];
#pragma unroll
    for (int i = 0; i < 8; ++i) acc += sp[i] * sd1_w[i * 768 + t];
    hid[t] = acc * sigmoidf_(acc);
    __syncthreads();
    if (t < 12) {
        float o = sd2_b[t];
        for (int d = 0; d < 768; ++d) o += hid[d] * sd2_w[d * 12 + t];
        scalef[b * 12 + t] = expf(o);
    }
}

// head: wave-per-row, lane owns 12 contiguous d; also emits rowlam = x.lam_w
__global__ __launch_bounds__(256) void head_kernel(const unsigned short* __restrict__ xn,
                                                   const float* __restrict__ head_w,
                                                   const float* __restrict__ head_b,
                                                   const float* __restrict__ scalef,
                                                   const float* __restrict__ lam_w,
                                                   float* __restrict__ out,
                                                   float* __restrict__ rowlam) {
    __shared__ float hw[768][13];
    __shared__ float red[4][64][14];
    int t = threadIdx.x, wave = t >> 6, lane = t & 63;
    for (int i = t; i < 768 * 12; i += 256) hw[i / 12][i % 12] = head_w[i];
    for (int i = t; i < 768; i += 256) hw[i][12] = lam_w[i];
    __syncthreads();
    int row_base = blockIdx.x * 64;
    for (int rr = wave; rr < 64; rr += 4) {
        int row = row_base + rr;
        const unsigned short* xr = xn + (size_t)row * 768 + lane * 12;
        float xv[12];
        u16x4 v0 = *(const u16x4*)(xr);
        u16x4 v1 = *(const u16x4*)(xr + 4);
        u16x4 v2 = *(const u16x4*)(xr + 8);
#pragma unroll
        for (int j = 0; j < 4; ++j) { xv[j] = b2f(v0[j]); xv[4 + j] = b2f(v1[j]); xv[8 + j] = b2f(v2[j]); }
        float p[13] = {};
        int d0 = lane * 12;
#pragma unroll
        for (int dd = 0; dd < 12; ++dd) {
            float xvv = xv[dd];
#pragma unroll
            for (int o = 0; o < 12; ++o) p[o] += xvv * hw[d0 + dd][o];
            p[12] += xvv * hw[d0 + dd][12];
        }
#pragma unroll
        for (int o = 0; o < 13; ++o) red[wave][lane][o] = p[o];
        __syncthreads();
        if (lane < 13) {
            float s = 0.f;
            for (int i = 0; i < 64; ++i) s += red[wave][i][lane];
            if (lane < 12) {
                int b = row >> 8, sidx = row & 255;
                float v = (s + head_b[lane]) * scalef[b * 12 + lane];
                int c = lane >> 2, py = (lane >> 1) & 1, px = lane & 1;
                int gy = sidx >> 4, gxx = sidx & 15;
                out[(((size_t)b * 3 + c) * 32 + 2 * gy + py) * 32 + 2 * gxx + px] = v;
            } else {
                rowlam[row] = s;
            }
        }
        __syncthreads();
    }
}

__global__ __launch_bounds__(256) void lpred_kernel(const float* __restrict__ rowlam,
                                                    const float* __restrict__ lam_b,
                                                    float* __restrict__ out) {
    int b = blockIdx.x, t = threadIdx.x;
    __shared__ float red[256];
    red[t] = rowlam[b * 256 + t];
    __syncthreads();
    for (int s2 = 128; s2 > 0; s2 >>= 1) { if (t < s2) red[t] += red[t + s2]; __syncthreads(); }
    if (t == 0) out[196608 + b] = red[0] / 256.0f + lam_b[0];
}

// ---------------------------------------------------------------------------
extern "C" void kernel_launch(void* const* d_in, const int* in_sizes, int n_in,
                              void* d_out, int out_size, void* d_ws, size_t ws_size,
                              hipStream_t stream) {
    const float* z_t     = (const float*)d_in[0];
    const float* logsnr  = (const float*)d_in[1];
    const float* qkv_w   = (const float*)d_in[2];
    const float* out_w   = (const float*)d_in[3];
    const float* gate_w  = (const float*)d_in[4];
    const float* gate_b  = (const float*)d_in[5];
    const float* mlpg_w  = (const float*)d_in[6];
    const float* mlpg_b  = (const float*)d_in[7];
    const float* mlpo_w  = (const float*)d_in[8];
    const float* mlpo_b  = (const float*)d_in[9];
    const float* hh_vs   = (const float*)d_in[10];
    const float* patch_w = (const float*)d_in[11];
    const float* patch_b = (const float*)d_in[12];
    const float* head_w  = (const float*)d_in[13];
    const float* head_b  = (const float*)d_in[14];
    const float* sd1_w   = (const float*)d_in[15];
    const float* sd1_b   = (const float*)d_in[16];
    const float* sd2_w   = (const float*)d_in[17];
    const float* sd2_b   = (const float*)d_in[18];
    const float* lam_w   = (const float*)d_in[19];
    const float* lam_b   = (const float*)d_in[20];

    char* wsb = (char*)d_ws;
    float* spins  = (float*)(wsb + B_SPINS);
    float* scalef = (float*)(wsb + B_SCALEF);
    float* qt     = (float*)(wsb + B_QT);
    float* cosb   = (float*)(wsb + B_COS);
    float* sinb   = (float*)(wsb + B_SIN);
    float* Gm     = (float*)(wsb + B_G);
    float* Tm     = (float*)(wsb + B_T);
    float* Am     = (float*)(wsb + B_AWY);
    float* rowlam = (float*)(wsb + B_ROWLAM);
    float* x      = (float*)(wsb + B_X);
    unsigned short* h      = (unsigned short*)(wsb + B_H);
    unsigned short* weff_t = (unsigned short*)(wsb + B_WEFFT);
    unsigned short* outw_t = (unsigned short*)(wsb + B_OUTWT);
    unsigned short* mlpg_t = (unsigned short*)(wsb + B_MLPGT);
    unsigned short* mlpo_t = (unsigned short*)(wsb + B_MLPOT);
    unsigned short* w2_t   = (unsigned short*)(wsb + B_W2T);
    unsigned short* arena  = (unsigned short*)(wsb + B_ARENA);
    unsigned short* qbuf = arena;
    unsigned short* kbuf = arena + ARENA_K;
    unsigned short* vtbuf = arena + 2 * ARENA_K;
    unsigned short* attnb = arena + 3 * ARENA_K;
    unsigned short* hidden = arena;
    float* out = (float*)d_out;

    // ---- setup ----
    spins_kernel<<<1, 64, 0, stream>>>(logsnr, spins);
    rope_table_kernel<<<256, 192, 0, stream>>>(cosb, sinb);
    hh_gram_kernel<<<8, 256, 0, stream>>>(hh_vs, Gm);
    hh_t_kernel<<<8, 128, 0, stream>>>(Gm, Tm);
    hh_a_kernel<<<8, 256, 0, stream>>>(Tm, hh_vs, Am);
    hh_p_kernel<<<8, 256, 0, stream>>>(hh_vs, Am, qt);
    fold_bf16t<<<dim3(3, 12, 64), 256, 0, stream>>>(qkv_w, qt, weff_t);
    transpose_bf16_kernel<<<dim3(24, 24, 8), 256, 0, stream>>>(qkv_w + 1536, 2304,
        (size_t)768 * 2304, weff_t + (size_t)1536 * 768, 768, (size_t)2304 * 768);
    transpose_bf16_kernel<<<dim3(24, 24, 8), 256, 0, stream>>>(out_w, 768,
        (size_t)768 * 768, outw_t, 768, (size_t)768 * 768);
    w2_bf16t<<<dim3(12, 12, 8), 256, 0, stream>>>(out_w, gate_w, w2_t);
    transpose_bf16_kernel<<<dim3(192, 24, 8), 256, 0, stream>>>(mlpg_w, 6144,
        (size_t)768 * 6144, mlpg_t, 768, (size_t)6144 * 768);
    transpose_bf16_kernel<<<dim3(24, 96, 8), 256, 0, stream>>>(mlpo_w, 768,
        (size_t)3072 * 768, mlpo_t, 3072, (size_t)768 * 3072);
    patch_embed_kernel<<<M_TOK, 256, 0, stream>>>(z_t, spins, patch_w, patch_b, x);

    for (int l = 0; l < Ll; ++l) {
        int glob = ((l + 1) % 4 == 0) ? 1 : 0;
        rmsnorm_kernel<<<4096, 256, 0, stream>>>(x, h);
        gemm_big<1><<<dim3(18, 64), 512, 0, stream>>>(h, 768,
            weff_t + (size_t)l * 2304 * 768, 768, arena, 0, 768, nullptr, nullptr, 3);
        attn_mfma_kernel<<<dim3(2, 4, 64), 512, 0, stream>>>(qbuf, kbuf, vtbuf, attnb,
            cosb, sinb, glob);
        gemm_projgate<<<dim3(12, 64), 512, 0, stream>>>(attnb,
            outw_t + (size_t)l * 768 * 768, w2_t + (size_t)l * 768 * 768,
            gate_b + (size_t)l * 768, x, 3);
        rmsnorm_kernel<<<4096, 256, 0, stream>>>(x, h);
        gemm_mlp_fused<<<dim3(48, 64), 512, 0, stream>>>(h,
            mlpg_t + (size_t)l * 6144 * 768, hidden, mlpg_b + (size_t)l * 6144, 4);
        gemm_big<4><<<dim3(6, 64), 512, 0, stream>>>(hidden, 3072,
            mlpo_t + (size_t)l * 768 * 3072, 3072, nullptr, 768, 3072,
            mlpo_b + (size_t)l * 768, x, 3);
    }

    rmsnorm_kernel<<<4096, 256, 0, stream>>>(x, h);
    scalef_kernel<<<64, 768, 0, stream>>>(spins, sd1_w, sd1_b, sd2_w, sd2_b, scalef);
    head_kernel<<<256, 256, 0, stream>>>(h, head_w, head_b, scalef, lam_w, out, rowlam);
    lpred_kernel<<<64, 256, 0, stream>>>(rowlam, lam_b, out);
}

// Round 19
// 5459.651 us; speedup vs baseline: 1.0308x; 1.0308x over previous
//
#include <hip/hip_runtime.h>
#include <hip/hip_bf16.h>
#include <math.h>

// ---------------------------------------------------------------------------
// HybridGemmaDiT forward.  B=64, S=256 (16x16), D=768, L=8, NH=4, HD=192.
// R19 = exact revert to R17 (best verified: 5.473 ms, absmax 0.03125).
// R18 showed gemm_big (256x128 single-buffer) is correct but -3% vs the
// 2-deep-pipelined 128^2 gemm_mfma; third confirmation that single-buffer
// big tiles lose to pipelined 128^2 on K=768-class GEMMs here.
// ---------------------------------------------------------------------------

#define DEV static __device__ __forceinline__

typedef float    f32x4 __attribute__((ext_vector_type(4)));
typedef short    s16x8 __attribute__((ext_vector_type(8)));
typedef unsigned short u16x8 __attribute__((ext_vector_type(8)));
typedef unsigned short u16x4 __attribute__((ext_vector_type(4)));

constexpr int Bb = 64, Ss = 256, Dd = 768, Ll = 8, NHh = 4, HDd = 192;
constexpr int M_TOK = Bb * Ss;                 // 16384
constexpr float EPS_RMS = 1.1920929e-07f;
constexpr float ATT_SCALE = 0.07216878364870322f;  // 1/sqrt(192)
constexpr size_t ARENA_K = (size_t)Bb * NHh * Ss * HDd;   // 12,582,912 elems

// ---- workspace layout (BYTES) ---------------------------------------------
constexpr size_t B_SPINS  = 0;
constexpr size_t B_SCALEF = 2048;
constexpr size_t B_QT     = 5120;                        // 8*192*192 f32
constexpr size_t B_COS    = B_QT + 1179648;
constexpr size_t B_SIN    = B_COS + 196608;
constexpr size_t B_G      = B_SIN + 196608;              // 8*96*96 f32
constexpr size_t B_T      = B_G + 294912;
constexpr size_t B_AWY    = B_T + 294912;                // 8*96*192 f32
constexpr size_t B_ROWLAM = B_AWY + 589824;              // 16384 f32
constexpr size_t B_X      = B_ROWLAM + 65536;            // 16384*768 f32
constexpr size_t B_H      = B_X + 50331648;              // bf16
constexpr size_t B_PROJ   = B_H + 25165824;              // bf16 (unused)
constexpr size_t B_WEFFT  = B_PROJ + 25165824;           // 8*2304*768 bf16
constexpr size_t B_OUTWT  = B_WEFFT + 28311552;
constexpr size_t B_GATEWT = B_OUTWT + 9437184;           // unused
constexpr size_t B_MLPGT  = B_GATEWT + 9437184;          // 8*6144*768 bf16
constexpr size_t B_MLPOT  = B_MLPGT + 75497472;          // 8*768*3072 bf16
constexpr size_t B_W2T    = B_MLPOT + 37748736;          // 8*768*768 bf16
constexpr size_t B_ARENA  = B_W2T + 9437184;             // q,k,v^T,attn bf16 | hidden

DEV float sigmoidf_(float x) { return 1.0f / (1.0f + expf(-x)); }
DEV float geluf_(float g)    { return 0.5f * g * (1.0f + erff(g * 0.7071067811865476f)); }
DEV unsigned short f2bf(float f) {
    union { float f; unsigned u; } a; a.f = f;
    unsigned u = a.u + 0x7fffu + ((a.u >> 16) & 1u);
    return (unsigned short)(u >> 16);
}
DEV float b2f(unsigned short u) {
    union { unsigned u; float f; } a; a.u = ((unsigned)u) << 16; return a.f;
}
DEV void gload16(const void* g, void* l) {
    __builtin_amdgcn_global_load_lds((const __attribute__((address_space(1))) void*)g,
                                     (__attribute__((address_space(3))) void*)l, 16, 0, 0);
}

// 2D-chunked XCD-aware swizzle (bijective when gy%8==0 and gx%CX==0)
DEV void xcd_chunk(int gx, int gy, int CX, int& bx, int& by) {
    int id = by * gx + bx;
    int c = id & 7;
    int s = id >> 3;
    int CY = gy >> 3;
    int subsz = CY * CX;
    int bxc = s / subsz;
    int r = s - bxc * subsz;
    int byl = r / CX;
    by = c * CY + byl;
    bx = bxc * CX + (r - byl * CX);
}

// ---------------------------------------------------------------------------
__global__ void spins_kernel(const float* __restrict__ logsnr, float* __restrict__ spins) {
    int b = threadIdx.x;
    if (b < 64) {
        float v = logsnr[b];
#pragma unroll
        for (int j = 0; j < 4; ++j) {
            float ang = v * (float)(1 << j);
            spins[b * 8 + j]     = sinf(ang);
            spins[b * 8 + 4 + j] = cosf(ang);
        }
    }
}

__global__ void rope_table_kernel(float* __restrict__ cosb, float* __restrict__ sinb) {
    int s = blockIdx.x, j = threadIdx.x;
    int y = s >> 4, x = s & 15;
    int base = j % 96;
    float coord, invf;
    if (base < 48) { invf = expf(-(float)base * (2.0f / 96.0f) * 9.210340371976184f); coord = (float)y; }
    else { int i = base - 48; invf = expf(-(float)i * (2.0f / 96.0f) * 9.210340371976184f); coord = (float)x; }
    float f = coord * invf, sv, cv;
    sincosf(f, &sv, &cv);
    cosb[s * 192 + j] = cv;
    sinb[s * 192 + j] = sv;
}

// ---- WY householder: qt = Q^T = I - Y^T T Y -------------------------------
__global__ __launch_bounds__(256) void hh_gram_kernel(const float* __restrict__ hh_vs,
                                                      float* __restrict__ Gm) {
    __shared__ float Y[96][192];
    int l = blockIdx.x, t = threadIdx.x;
    const float4* src = (const float4*)(hh_vs + (size_t)l * 96 * 192);
    for (int i = t; i < 4608; i += 256) ((float4*)&Y[0][0])[i] = src[i];
    __syncthreads();
    for (int e = t; e < 9216; e += 256) {
        int i = e / 96, j = e - (e / 96) * 96;
        float acc = 0.f;
        for (int d = 0; d < 48; ++d) {
            float4 a = *(const float4*)&Y[i][d * 4];
            float4 b = *(const float4*)&Y[j][d * 4];
            acc += a.x * b.x + a.y * b.y + a.z * b.z + a.w * b.w;
        }
        Gm[(size_t)l * 9216 + e] = acc;
    }
}

__global__ __launch_bounds__(128) void hh_t_kernel(const float* __restrict__ Gm,
                                                   float* __restrict__ Tm) {
    __shared__ float G[96][96];
    __shared__ float Tt[96][96];
    int l = blockIdx.x, t = threadIdx.x;
    const float* Gl = Gm + (size_t)l * 9216;
    for (int i = t; i < 9216; i += 128) { ((float*)G)[i] = Gl[i]; ((float*)Tt)[i] = 0.f; }
    __syncthreads();
    if (t < 96) Tt[t][t] = 2.0f / (G[t][t] + 1e-8f);
    __syncthreads();
    for (int j = 1; j < 96; ++j) {
        if (t < 96) {
            float cj = 2.0f / (G[j][j] + 1e-8f);
            float dot = 0.f;
            for (int p = 0; p < j; ++p) dot += Tt[p][t] * G[p][j];
            if (t < j) Tt[j][t] = -cj * dot;
        }
        __syncthreads();
    }
    for (int i = t; i < 9216; i += 128) Tm[(size_t)l * 9216 + i] = ((float*)Tt)[i];
}

__global__ __launch_bounds__(256) void hh_a_kernel(const float* __restrict__ Tm,
                                                   const float* __restrict__ hh_vs,
                                                   float* __restrict__ Am) {
    __shared__ float T[96][96];
    __shared__ float Y[96][192];
    int l = blockIdx.x, t = threadIdx.x;
    const float* Tl = Tm + (size_t)l * 9216;
    const float4* src = (const float4*)(hh_vs + (size_t)l * 96 * 192);
    for (int i = t; i < 9216; i += 256) ((float*)T)[i] = Tl[i];
    for (int i = t; i < 4608; i += 256) ((float4*)&Y[0][0])[i] = src[i];
    __syncthreads();
    for (int idx = t; idx < 4608; idx += 256) {
        int i = idx / 48, e0 = (idx % 48) * 4;
        float4 acc = {0.f, 0.f, 0.f, 0.f};
        for (int j = i; j < 96; ++j) {
            float tv = T[j][i];
            float4 y = *(const float4*)&Y[j][e0];
            acc.x += tv * y.x; acc.y += tv * y.y; acc.z += tv * y.z; acc.w += tv * y.w;
        }
        *(float4*)(Am + (size_t)l * 96 * 192 + (size_t)i * 192 + e0) = acc;
    }
}

__global__ __launch_bounds__(256) void hh_p_kernel(const float* __restrict__ hh_vs,
                                                   const float* __restrict__ Am,
                                                   float* __restrict__ qt) {
    __shared__ float Y[96][192];
    __shared__ float A[96][192];
    int l = blockIdx.x, t = threadIdx.x;
    const float4* ys = (const float4*)(hh_vs + (size_t)l * 96 * 192);
    const float4* as = (const float4*)(Am + (size_t)l * 96 * 192);
    for (int i = t; i < 4608; i += 256) { ((float4*)&Y[0][0])[i] = ys[i]; ((float4*)&A[0][0])[i] = as[i]; }
    __syncthreads();
    for (int idx = t; idx < 9216; idx += 256) {
        int d = idx / 48, e0 = (idx % 48) * 4;
        float4 acc = {0.f, 0.f, 0.f, 0.f};
        for (int i = 0; i < 96; ++i) {
            float yv = Y[i][d];
            float4 a = *(const float4*)&A[i][e0];
            acc.x += yv * a.x; acc.y += yv * a.y; acc.z += yv * a.z; acc.w += yv * a.w;
        }
        acc.x = (d == e0 + 0 ? 1.f : 0.f) - acc.x;
        acc.y = (d == e0 + 1 ? 1.f : 0.f) - acc.y;
        acc.z = (d == e0 + 2 ? 1.f : 0.f) - acc.z;
        acc.w = (d == e0 + 3 ? 1.f : 0.f) - acc.w;
        *(float4*)(qt + (size_t)l * 192 * 192 + (size_t)d * 192 + e0) = acc;
    }
}

// fold + transpose + bf16 in one: weff_t[n][k] = sum_d qkv_w[k][d] qt[d][n]
__global__ __launch_bounds__(256) void fold_bf16t(const float* __restrict__ qkv_w,
                                                  const float* __restrict__ qt,
                                                  unsigned short* __restrict__ weff_t) {
    int z = blockIdx.z;
    int l = z >> 3, which = (z >> 2) & 1, head = z & 3;
    const float* A  = qkv_w + (size_t)l * 768 * 2304 + (size_t)which * 768 + head * 192;
    const float* Bq = qt + (size_t)l * 192 * 192;
    unsigned short* C = weff_t + (size_t)l * 2304 * 768 + ((size_t)which * 768 + head * 192) * 768;
    int row0 = blockIdx.y * 64, col0 = blockIdx.x * 64;
    __shared__ float As[64][65];
    __shared__ float Bs[64][65];
    int tid = threadIdx.x, tx = tid & 15, ty = tid >> 4;
    float acc[4][4] = {};
    for (int k0 = 0; k0 < 192; k0 += 64) {
        for (int i = tid; i < 1024; i += 256) {
            int r = i >> 4, kq = i & 15;
            float4 va = *(const float4*)(A + (size_t)(row0 + r) * 2304 + k0 + kq * 4);
            As[kq * 4 + 0][r] = va.x; As[kq * 4 + 1][r] = va.y; As[kq * 4 + 2][r] = va.z; As[kq * 4 + 3][r] = va.w;
        }
        for (int i = tid; i < 1024; i += 256) {
            int r = i >> 4, nq = i & 15;
            float4 vb = *(const float4*)(Bq + (size_t)(k0 + r) * 192 + col0 + nq * 4);
            Bs[r][nq * 4 + 0] = vb.x; Bs[r][nq * 4 + 1] = vb.y; Bs[r][nq * 4 + 2] = vb.z; Bs[r][nq * 4 + 3] = vb.w;
        }
        __syncthreads();
        for (int k = 0; k < 64; ++k) {
            float a[4], bb[4];
#pragma unroll
            for (int m = 0; m < 4; ++m) a[m] = As[k][ty * 4 + m];
#pragma unroll
            for (int n = 0; n < 4; ++n) bb[n] = Bs[k][tx * 4 + n];
#pragma unroll
            for (int m = 0; m < 4; ++m)
#pragma unroll
                for (int n = 0; n < 4; ++n) acc[m][n] = fmaf(a[m], bb[n], acc[m][n]);
        }
        __syncthreads();
    }
    float (*Tr)[65] = (float(*)[65])As;
#pragma unroll
    for (int m = 0; m < 4; ++m)
#pragma unroll
        for (int n = 0; n < 4; ++n) Tr[tx * 4 + n][ty * 4 + m] = acc[m][n];
    __syncthreads();
    int nl = tid >> 2, kc = (tid & 3) * 16;
#pragma unroll
    for (int q4 = 0; q4 < 4; ++q4) {
        u16x4 o;
#pragma unroll
        for (int ii = 0; ii < 4; ++ii) o[ii] = f2bf(Tr[nl][kc + q4 * 4 + ii]);
        *(u16x4*)(C + (size_t)(col0 + nl) * 768 + row0 + kc + q4 * 4) = o;
    }
}

// W2t[n][k] = sum_d out_w[k][d] * gate_w[d][n]  (fp32 in, bf16 [n][k] out)
__global__ __launch_bounds__(256) void w2_bf16t(const float* __restrict__ ow,
                                                const float* __restrict__ gw,
                                                unsigned short* __restrict__ w2t) {
    int l = blockIdx.z;
    const float* A = ow + (size_t)l * 768 * 768;
    const float* B = gw + (size_t)l * 768 * 768;
    unsigned short* C = w2t + (size_t)l * 768 * 768;
    int row0 = blockIdx.y * 64, col0 = blockIdx.x * 64;
    __shared__ float As[64][65];
    __shared__ float Bs[64][65];
    int tid = threadIdx.x, tx = tid & 15, ty = tid >> 4;
    float acc[4][4] = {};
    for (int k0 = 0; k0 < 768; k0 += 64) {
        for (int i = tid; i < 1024; i += 256) {
            int r = i >> 4, kq = i & 15;
            float4 va = *(const float4*)(A + (size_t)(row0 + r) * 768 + k0 + kq * 4);
            As[kq * 4 + 0][r] = va.x; As[kq * 4 + 1][r] = va.y; As[kq * 4 + 2][r] = va.z; As[kq * 4 + 3][r] = va.w;
        }
        for (int i = tid; i < 1024; i += 256) {
            int r = i >> 4, nq = i & 15;
            float4 vb = *(const float4*)(B + (size_t)(k0 + r) * 768 + col0 + nq * 4);
            Bs[r][nq * 4 + 0] = vb.x; Bs[r][nq * 4 + 1] = vb.y; Bs[r][nq * 4 + 2] = vb.z; Bs[r][nq * 4 + 3] = vb.w;
        }
        __syncthreads();
        for (int k = 0; k < 64; ++k) {
            float a[4], bb[4];
#pragma unroll
            for (int m = 0; m < 4; ++m) a[m] = As[k][ty * 4 + m];
#pragma unroll
            for (int n = 0; n < 4; ++n) bb[n] = Bs[k][tx * 4 + n];
#pragma unroll
            for (int m = 0; m < 4; ++m)
#pragma unroll
                for (int n = 0; n < 4; ++n) acc[m][n] = fmaf(a[m], bb[n], acc[m][n]);
        }
        __syncthreads();
    }
    float (*Tr)[65] = (float(*)[65])As;
#pragma unroll
    for (int m = 0; m < 4; ++m)
#pragma unroll
        for (int n = 0; n < 4; ++n) Tr[tx * 4 + n][ty * 4 + m] = acc[m][n];
    __syncthreads();
    int nl = tid >> 2, kc = (tid & 3) * 16;
#pragma unroll
    for (int q4 = 0; q4 < 4; ++q4) {
        u16x4 o;
#pragma unroll
        for (int ii = 0; ii < 4; ++ii) o[ii] = f2bf(Tr[nl][kc + q4 * 4 + ii]);
        *(u16x4*)(C + (size_t)(col0 + nl) * 768 + row0 + kc + q4 * 4) = o;
    }
}

// strided fp32 [K][N] -> bf16 [N][K]
__global__ __launch_bounds__(256) void transpose_bf16_kernel(const float* __restrict__ W,
                                                             int ldw, size_t zsrc,
                                                             unsigned short* __restrict__ Wt,
                                                             int ldwt, size_t zdst) {
    __shared__ float t[32][33];
    const float* Wz = W + (size_t)blockIdx.z * zsrc;
    unsigned short* Wtz = Wt + (size_t)blockIdx.z * zdst;
    int k0 = blockIdx.y * 32, n0 = blockIdx.x * 32;
    int tid = threadIdx.x;
    int tr = tid >> 3, tc = tid & 7;
    float4 v = *(const float4*)(Wz + (size_t)(k0 + tr) * ldw + n0 + tc * 4);
    t[tr][tc * 4 + 0] = v.x; t[tr][tc * 4 + 1] = v.y; t[tr][tc * 4 + 2] = v.z; t[tr][tc * 4 + 3] = v.w;
    __syncthreads();
    u16x4 o;
    o[0] = f2bf(t[tc * 4 + 0][tr]); o[1] = f2bf(t[tc * 4 + 1][tr]);
    o[2] = f2bf(t[tc * 4 + 2][tr]); o[3] = f2bf(t[tc * 4 + 3][tr]);
    *(u16x4*)(Wtz + (size_t)(n0 + tr) * ldwt + k0 + tc * 4) = o;
}

__global__ __launch_bounds__(256) void patch_embed_kernel(const float* __restrict__ z_t,
                                                          const float* __restrict__ spins,
                                                          const float* __restrict__ patch_w,
                                                          const float* __restrict__ patch_b,
                                                          float* __restrict__ x) {
    int bs = blockIdx.x;
    int b = bs >> 8, s = bs & 255;
    int gy = s >> 4, gx = s & 15;
    __shared__ float in20[20];
    int t = threadIdx.x;
    if (t < 12) {
        int c = t >> 2, py = (t >> 1) & 1, px = t & 1;
        in20[t] = z_t[(((size_t)b * 3 + c) * 32 + (2 * gy + py)) * 32 + (2 * gx + px)];
    } else if (t < 20) {
        in20[t] = spins[b * 8 + (t - 12)];
    }
    __syncthreads();
    for (int d = t; d < 768; d += 256) {
        float acc = patch_b[d];
#pragma unroll
        for (int i = 0; i < 20; ++i) acc += in20[i] * patch_w[i * 768 + d];
        x[(size_t)bs * 768 + d] = acc;
    }
}

// wave-per-row rmsnorm: 4 rows/block, lane owns 12 contiguous d
__global__ __launch_bounds__(256) void rmsnorm_kernel(const float* __restrict__ x,
                                                      unsigned short* __restrict__ h) {
    int wave = threadIdx.x >> 6, lane = threadIdx.x & 63;
    int row = blockIdx.x * 4 + wave;
    const float* xr = x + (size_t)row * 768 + lane * 12;
    float4 a = *(const float4*)(xr);
    float4 b = *(const float4*)(xr + 4);
    float4 c = *(const float4*)(xr + 8);
    float ss = a.x*a.x + a.y*a.y + a.z*a.z + a.w*a.w
             + b.x*b.x + b.y*b.y + b.z*b.z + b.w*b.w
             + c.x*c.x + c.y*c.y + c.z*c.z + c.w*c.w;
#pragma unroll
    for (int msk = 1; msk < 64; msk <<= 1) ss += __shfl_xor(ss, msk);
    float sc = 1.0f / sqrtf(ss / 768.0f + EPS_RMS);
    unsigned short* hr = h + (size_t)row * 768 + lane * 12;
    u16x4 o0, o1, o2;
    o0[0]=f2bf(a.x*sc); o0[1]=f2bf(a.y*sc); o0[2]=f2bf(a.z*sc); o0[3]=f2bf(a.w*sc);
    o1[0]=f2bf(b.x*sc); o1[1]=f2bf(b.y*sc); o1[2]=f2bf(b.z*sc); o1[3]=f2bf(b.w*sc);
    o2[0]=f2bf(c.x*sc); o2[1]=f2bf(c.y*sc); o2[2]=f2bf(c.z*sc); o2[3]=f2bf(c.w*sc);
    *(u16x4*)(hr) = o0; *(u16x4*)(hr + 4) = o1; *(u16x4*)(hr + 8) = o2;
}

// ---- bf16 MFMA GEMM: 128x128, BK=32, 2-deep pipeline, chunked XCD ---------
// EPI: 1=qkv scatter (V transposed)  4=x+=v
template <int EPI>
__global__ __launch_bounds__(256) void gemm_mfma(const unsigned short* __restrict__ A, int lda,
                                                 const unsigned short* __restrict__ Bt, int ldb,
                                                 unsigned short* __restrict__ Cb, int ldc, int K,
                                                 const float* __restrict__ bias,
                                                 float* __restrict__ Xf,
                                                 const unsigned short* __restrict__ Pb,
                                                 int CX) {
    __shared__ unsigned short As[2][4096];
    __shared__ unsigned short Bs[2][4096];
    int tid = threadIdx.x;
    int wave = tid >> 6, lane = tid & 63;
    int bx = blockIdx.x, by = blockIdx.y;
    xcd_chunk(gridDim.x, gridDim.y, CX, bx, by);
    int row0 = by * 128, col0 = bx * 128;
    int wm = wave >> 1, wn = wave & 1;
    f32x4 acc[4][4] = {};

    int srow = lane >> 2;
    int ksw = (((lane & 3) ^ (srow & 3)) * 8);
    int lrow = lane & 15;
    int csw = (((lane >> 4) ^ (lane & 3)) * 8);

    auto stage = [&](int buf, int k0) {
#pragma unroll
        for (int it = 0; it < 2; ++it) {
            int chunk = it * 4 + wave;
            int r = chunk * 16 + srow;
            gload16(A  + (size_t)(row0 + r) * lda + k0 + ksw, &As[buf][chunk * 512]);
            gload16(Bt + (size_t)(col0 + r) * ldb + k0 + ksw, &Bs[buf][chunk * 512]);
        }
    };

    int NT = K >> 5;
    stage(0, 0);
    for (int t = 0; t < NT; ++t) {
        if (t + 1 < NT) {
            stage((t + 1) & 1, (t + 1) << 5);
            asm volatile("s_waitcnt vmcnt(4)" ::: "memory");
        } else {
            asm volatile("s_waitcnt vmcnt(0)" ::: "memory");
        }
        __builtin_amdgcn_s_barrier();
        const unsigned short* Ab = As[t & 1];
        const unsigned short* Bb = Bs[t & 1];
        s16x8 af[4], bf[4];
#pragma unroll
        for (int m = 0; m < 4; ++m)
            af[m] = *(const s16x8*)&Ab[(wm * 64 + m * 16 + lrow) * 32 + csw];
#pragma unroll
        for (int n = 0; n < 4; ++n)
            bf[n] = *(const s16x8*)&Bb[(wn * 64 + n * 16 + lrow) * 32 + csw];
#pragma unroll
        for (int m = 0; m < 4; ++m)
#pragma unroll
            for (int n = 0; n < 4; ++n)
                acc[m][n] = __builtin_amdgcn_mfma_f32_16x16x32_bf16(af[m], bf[n], acc[m][n], 0, 0, 0);
        __builtin_amdgcn_s_barrier();
    }

    int lquad = lane >> 4;
#pragma unroll
    for (int m = 0; m < 4; ++m) {
#pragma unroll
        for (int n = 0; n < 4; ++n) {
#pragma unroll
            for (int r = 0; r < 4; ++r) {
                int i = row0 + wm * 64 + m * 16 + lquad * 4 + r;
                int j = col0 + wn * 64 + n * 16 + lrow;
                float v = acc[m][n][r];
                if (bias) v += bias[j];
                if constexpr (EPI == 1) {
                    int which = j / 768;
                    int rem = j - which * 768;
                    int head = rem / 192;
                    int hd = rem - head * 192;
                    int b = i >> 8, s = i & 255;
                    if (which == 2) {   // V transposed: [bh][d][s]
                        Cb[2 * ARENA_K + (((size_t)(b * 4 + head)) * 192 + hd) * 256 + s] = f2bf(v);
                    } else {
                        Cb[(size_t)which * ARENA_K + (((size_t)(b * 4 + head)) * 256 + s) * 192 + hd] = f2bf(v);
                    }
                } else if constexpr (EPI == 4) {
                    Xf[(size_t)i * ldc + j] += v;
                }
            }
        }
    }
}

// ---- fused MLP-in GEMM: 256Mx64N, 8 waves, single-buffer ------------------
__global__ __launch_bounds__(512) void gemm_mlp_fused(const unsigned short* __restrict__ A,
                                                      const unsigned short* __restrict__ Bt,
                                                      unsigned short* __restrict__ Hid,
                                                      const float* __restrict__ bias,
                                                      int CX) {
    __shared__ unsigned short As[8192];
    __shared__ unsigned short Bs[8192];
    int tid = threadIdx.x;
    int wave = tid >> 6, lane = tid & 63;
    int bx = blockIdx.x, by = blockIdx.y;
    xcd_chunk(gridDim.x, gridDim.y, CX, bx, by);
    int row0 = by * 256, col0 = bx * 64;
    int wm = wave >> 1, wn = wave & 1;
    f32x4 accg[4][2] = {};
    f32x4 accv[4][2] = {};

    int srow = lane >> 2;
    int ksw = (((lane & 3) ^ (srow & 3)) * 8);
    int lrow = lane & 15;
    int csw = (((lane >> 4) ^ (lane & 3)) * 8);

    const unsigned short* Bg = Bt + (size_t)col0 * 768;
    const unsigned short* Bv = Bt + (size_t)(3072 + col0) * 768;

    for (int k0 = 0; k0 < 768; k0 += 32) {
#pragma unroll
        for (int it = 0; it < 2; ++it) {
            int chunk = it * 8 + wave;
            int r = chunk * 16 + srow;
            gload16(A + (size_t)(row0 + r) * 768 + k0 + ksw, &As[chunk * 512]);
        }
        {
            int half = wave >> 2;
            int chunk = wave & 3;
            int r = chunk * 16 + srow;
            const unsigned short* Bh = half ? Bv : Bg;
            gload16(Bh + (size_t)r * 768 + k0 + ksw, &Bs[half * 4096 + chunk * 512]);
        }
        __syncthreads();
        s16x8 af[4], bgf[2], bvf[2];
#pragma unroll
        for (int m = 0; m < 4; ++m)
            af[m] = *(const s16x8*)&As[(wm * 64 + m * 16 + lrow) * 32 + csw];
#pragma unroll
        for (int n = 0; n < 2; ++n) {
            bgf[n] = *(const s16x8*)&Bs[(wn * 32 + n * 16 + lrow) * 32 + csw];
            bvf[n] = *(const s16x8*)&Bs[4096 + (wn * 32 + n * 16 + lrow) * 32 + csw];
        }
#pragma unroll
        for (int m = 0; m < 4; ++m)
#pragma unroll
            for (int n = 0; n < 2; ++n) {
                accg[m][n] = __builtin_amdgcn_mfma_f32_16x16x32_bf16(af[m], bgf[n], accg[m][n], 0, 0, 0);
                accv[m][n] = __builtin_amdgcn_mfma_f32_16x16x32_bf16(af[m], bvf[n], accv[m][n], 0, 0, 0);
            }
        __syncthreads();
    }

    int lquad = lane >> 4;
#pragma unroll
    for (int m = 0; m < 4; ++m) {
#pragma unroll
        for (int n = 0; n < 2; ++n) {
#pragma unroll
            for (int r = 0; r < 4; ++r) {
                int i = row0 + wm * 64 + m * 16 + lquad * 4 + r;
                int j = col0 + wn * 32 + n * 16 + lrow;
                float g = accg[m][n][r] + bias[j];
                float v = accv[m][n][r] + bias[3072 + j];
                Hid[(size_t)i * 3072 + j] = f2bf(v * geluf_(g));
            }
        }
    }
}

// ---- fused proj+gate GEMM: 256Mx64N, 8 waves ------------------------------
__global__ __launch_bounds__(512) void gemm_projgate(const unsigned short* __restrict__ A,
                                                     const unsigned short* __restrict__ B1t,
                                                     const unsigned short* __restrict__ B2t,
                                                     const float* __restrict__ gate_b,
                                                     float* __restrict__ Xf,
                                                     int CX) {
    __shared__ unsigned short As[8192];
    __shared__ unsigned short Bs[8192];
    int tid = threadIdx.x;
    int wave = tid >> 6, lane = tid & 63;
    int bx = blockIdx.x, by = blockIdx.y;
    xcd_chunk(gridDim.x, gridDim.y, CX, bx, by);
    int row0 = by * 256, col0 = bx * 64;
    int wm = wave >> 1, wn = wave & 1;
    f32x4 accp[4][2] = {};
    f32x4 accg[4][2] = {};

    int srow = lane >> 2;
    int ksw = (((lane & 3) ^ (srow & 3)) * 8);
    int lrow = lane & 15;
    int csw = (((lane >> 4) ^ (lane & 3)) * 8);

    const unsigned short* B1 = B1t + (size_t)col0 * 768;
    const unsigned short* B2 = B2t + (size_t)col0 * 768;

    for (int k0 = 0; k0 < 768; k0 += 32) {
#pragma unroll
        for (int it = 0; it < 2; ++it) {
            int chunk = it * 8 + wave;
            int r = chunk * 16 + srow;
            gload16(A + (size_t)(row0 + r) * 768 + k0 + ksw, &As[chunk * 512]);
        }
        {
            int half = wave >> 2;
            int chunk = wave & 3;
            int r = chunk * 16 + srow;
            const unsigned short* Bh = half ? B2 : B1;
            gload16(Bh + (size_t)r * 768 + k0 + ksw, &Bs[half * 4096 + chunk * 512]);
        }
        __syncthreads();
        s16x8 af[4], b1f[2], b2f_[2];
#pragma unroll
        for (int m = 0; m < 4; ++m)
            af[m] = *(const s16x8*)&As[(wm * 64 + m * 16 + lrow) * 32 + csw];
#pragma unroll
        for (int n = 0; n < 2; ++n) {
            b1f[n]  = *(const s16x8*)&Bs[(wn * 32 + n * 16 + lrow) * 32 + csw];
            b2f_[n] = *(const s16x8*)&Bs[4096 + (wn * 32 + n * 16 + lrow) * 32 + csw];
        }
#pragma unroll
        for (int m = 0; m < 4; ++m)
#pragma unroll
            for (int n = 0; n < 2; ++n) {
                accp[m][n] = __builtin_amdgcn_mfma_f32_16x16x32_bf16(af[m], b1f[n],  accp[m][n], 0, 0, 0);
                accg[m][n] = __builtin_amdgcn_mfma_f32_16x16x32_bf16(af[m], b2f_[n], accg[m][n], 0, 0, 0);
            }
        __syncthreads();
    }

    int lquad = lane >> 4;
#pragma unroll
    for (int m = 0; m < 4; ++m) {
#pragma unroll
        for (int n = 0; n < 2; ++n) {
#pragma unroll
            for (int r = 0; r < 4; ++r) {
                int i = row0 + wm * 64 + m * 16 + lquad * 4 + r;
                int j = col0 + wn * 32 + n * 16 + lrow;
                float p1 = accp[m][n][r];
                float p2 = accg[m][n][r] + gate_b[j];
                Xf[(size_t)i * 768 + j] += p1 * sigmoidf_(p2);
            }
        }
    }
}

// ---- MFMA attention: fused RoPE + exact local skip + band-limited staging -
__global__ __launch_bounds__(512) void attn_mfma_kernel(const unsigned short* __restrict__ qb_,
                                                        const unsigned short* __restrict__ kb_,
                                                        const unsigned short* __restrict__ vtb_,
                                                        unsigned short* __restrict__ attnb,
                                                        const float* __restrict__ cosb,
                                                        const float* __restrict__ sinb,
                                                        int glob) {
    __shared__ unsigned short Klds[256 * 200];
    __shared__ unsigned short Vlds[192 * 72];
    __shared__ unsigned short Plds[8 * 16 * 72];
    int b = blockIdx.z, hh = blockIdx.y;
    int tid = threadIdx.x;
    int wave = tid >> 6, lane = tid & 63;
    int bxs = (int)blockIdx.x;
    int q0 = bxs * 128 + wave * 16;
    int yq = q0 >> 4;
    size_t bh = (size_t)(b * 4 + hh);
    const unsigned short* qb  = qb_  + bh * 49152;
    const unsigned short* kb  = kb_  + bh * 49152;
    const unsigned short* vtb = vtb_ + bh * 49152;

    // K rows needed by this block: y in [bxs*8-2, bxs*8+9] on local layers
    int rlo, rhi;
    if (glob) { rlo = 0; rhi = 256; }
    else {
        int lo = (bxs * 8 - 2) * 16;  if (lo < 0) lo = 0;
        int hi = (bxs * 8 + 10) * 16; if (hi > 256) hi = 256;
        rlo = lo; rhi = hi;
    }

    for (int c = tid; c < 6144; c += 512) {
        int r = c / 24, col = c - (c / 24) * 24;
        if (r < rlo || r >= rhi) continue;
        int j0 = col * 8;
        int jp = j0 < 96 ? j0 + 96 : j0 - 96;
        float sgn = j0 < 96 ? -1.f : 1.f;
        u16x8 a = *(const u16x8*)(kb + (size_t)r * 192 + j0);
        u16x8 p = *(const u16x8*)(kb + (size_t)r * 192 + jp);
        const float* cr = cosb + r * 192 + j0;
        const float* sr = sinb + r * 192 + j0;
        u16x8 o;
#pragma unroll
        for (int i = 0; i < 8; ++i)
            o[i] = f2bf(b2f(a[i]) * cr[i] + sgn * b2f(p[i]) * sr[i]);
        *(u16x8*)&Klds[r * 200 + j0] = o;
    }
    __syncthreads();

    s16x8 qf[6];
    {
        int sq = q0 + (lane & 15);
        const unsigned short* qrow = qb + (size_t)sq * 192;
        const float* cr = cosb + sq * 192;
        const float* sr = sinb + sq * 192;
#pragma unroll
        for (int kk = 0; kk < 6; ++kk) {
            int ck = kk * 32 + (lane >> 4) * 8;
            int cp = ck < 96 ? ck + 96 : ck - 96;
            float sgn = ck < 96 ? -1.f : 1.f;
            u16x8 a = *(const u16x8*)(qrow + ck);
            u16x8 p = *(const u16x8*)(qrow + cp);
            s16x8 o;
#pragma unroll
            for (int i = 0; i < 8; ++i)
                o[i] = (short)f2bf(b2f(a[i]) * cr[ck + i] + sgn * b2f(p[i]) * sr[ck + i]);
            qf[kk] = o;
        }
    }

    f32x4 sc[16];
#pragma unroll
    for (int n = 0; n < 16; ++n) sc[n] = (f32x4){0.f, 0.f, 0.f, 0.f};
#pragma unroll
    for (int kk = 0; kk < 6; ++kk) {
#pragma unroll
        for (int n = 0; n < 16; ++n) {
            if (glob || (n >= yq - 2 && n <= yq + 2)) {
                s16x8 bf = *(const s16x8*)&Klds[(n * 16 + (lane & 15)) * 200 + kk * 32 + (lane >> 4) * 8];
                sc[n] = __builtin_amdgcn_mfma_f32_16x16x32_bf16(qf[kk], bf, sc[n], 0, 0, 0);
            }
        }
    }

    int lq = (lane >> 4) * 4;
#pragma unroll
    for (int n = 0; n < 16; ++n) {
        int sk = n * 16 + (lane & 15);
        int yk = sk >> 4, xk = sk & 15;
#pragma unroll
        for (int r = 0; r < 4; ++r) {
            int sq = q0 + lq + r;
            int dy = (sq >> 4) - yk, dx = (sq & 15) - xk;
            bool keep = glob || (dy * dy + dx * dx) < 7;
            sc[n][r] = keep ? sc[n][r] * ATT_SCALE : -1e30f;
        }
    }
    float rmax[4], rsum[4];
#pragma unroll
    for (int r = 0; r < 4; ++r) {
        float m = sc[0][r];
#pragma unroll
        for (int n = 1; n < 16; ++n) m = fmaxf(m, sc[n][r]);
#pragma unroll
        for (int msk = 1; msk < 16; msk <<= 1) m = fmaxf(m, __shfl_xor(m, msk));
        rmax[r] = m;
    }
#pragma unroll
    for (int r = 0; r < 4; ++r) {
        float e = 0.f;
#pragma unroll
        for (int n = 0; n < 16; ++n) { float p = expf(sc[n][r] - rmax[r]); sc[n][r] = p; e += p; }
#pragma unroll
        for (int msk = 1; msk < 16; msk <<= 1) e += __shfl_xor(e, msk);
        rsum[r] = 1.0f / e;
    }

    f32x4 o[12];
#pragma unroll
    for (int n = 0; n < 12; ++n) o[n] = (f32x4){0.f, 0.f, 0.f, 0.f};
    unsigned short* Pw = &Plds[wave * 1152];
    int ylo = bxs * 8 - 2, yhi = bxs * 8 + 9;
    for (int kt = 0; kt < 4; ++kt) {
        if (!glob && !((4 * kt + 3 >= ylo) && (4 * kt <= yhi))) continue;
#pragma unroll
        for (int nn = 0; nn < 4; ++nn) {
#pragma unroll
            for (int r = 0; r < 4; ++r)
                Pw[(lq + r) * 72 + nn * 16 + (lane & 15)] = f2bf(sc[kt * 4 + nn][r] * rsum[r]);
        }
        __syncthreads();
        for (int c = tid; c < 1536; c += 512) {
            int r = c >> 3, col = c & 7;
            *(u16x8*)&Vlds[r * 72 + col * 8] = *(const u16x8*)(vtb + (size_t)r * 256 + kt * 64 + col * 8);
        }
        __syncthreads();
        s16x8 af[2];
#pragma unroll
        for (int kk2 = 0; kk2 < 2; ++kk2)
            af[kk2] = *(const s16x8*)&Pw[(lane & 15) * 72 + kk2 * 32 + (lane >> 4) * 8];
#pragma unroll
        for (int n = 0; n < 12; ++n) {
#pragma unroll
            for (int kk2 = 0; kk2 < 2; ++kk2) {
                s16x8 bf = *(const s16x8*)&Vlds[(n * 16 + (lane & 15)) * 72 + kk2 * 32 + (lane >> 4) * 8];
                o[n] = __builtin_amdgcn_mfma_f32_16x16x32_bf16(af[kk2], bf, o[n], 0, 0, 0);
            }
        }
    }
#pragma unroll
    for (int n = 0; n < 12; ++n) {
        int d = n * 16 + (lane & 15);
#pragma unroll
        for (int r = 0; r < 4; ++r) {
            int sq = q0 + lq + r;
            attnb[((size_t)(b * 256 + sq)) * 768 + hh * 192 + d] = f2bf(o[n][r]);
        }
    }
}

__global__ __launch_bounds__(768) void scalef_kernel(const float* __restrict__ spins,
                                                     const float* __restrict__ sd1_w,
                                                     const float* __restrict__ sd1_b,
                                                     const float* __restrict__ sd2_w,
                                                     const float* __restrict__ sd2_b,
                                                     float* __restrict__ scalef) {
    int b = blockIdx.x, t = threadIdx.x;
    __shared__ float hid[768];
    __shared__ float sp[8];
    if (t < 8) sp[t] = spins[b * 8 + t];
    __syncthreads();
    float acc = sd1_b[t];
#pragma unroll
    for (int i = 0; i < 8; ++i) acc += sp[i] * sd1_w[i * 768 + t];
    hid[t] = acc * sigmoidf_(acc);
    __syncthreads();
    if (t < 12) {
        float o = sd2_b[t];
        for (int d = 0; d < 768; ++d) o += hid[d] * sd2_w[d * 12 + t];
        scalef[b * 12 + t] = expf(o);
    }
}

// head: wave-per-row, lane owns 12 contiguous d; also emits rowlam = x.lam_w
__global__ __launch_bounds__(256) void head_kernel(const unsigned short* __restrict__ xn,
                                                   const float* __restrict__ head_w,
                                                   const float* __restrict__ head_b,
                                                   const float* __restrict__ scalef,
                                                   const float* __restrict__ lam_w,
                                                   float* __restrict__ out,
                                                   float* __restrict__ rowlam) {
    __shared__ float hw[768][13];
    __shared__ float red[4][64][14];
    int t = threadIdx.x, wave = t >> 6, lane = t & 63;
    for (int i = t; i < 768 * 12; i += 256) hw[i / 12][i % 12] = head_w[i];
    for (int i = t; i < 768; i += 256) hw[i][12] = lam_w[i];
    __syncthreads();
    int row_base = blockIdx.x * 64;
    for (int rr = wave; rr < 64; rr += 4) {
        int row = row_base + rr;
        const unsigned short* xr = xn + (size_t)row * 768 + lane * 12;
        float xv[12];
        u16x4 v0 = *(const u16x4*)(xr);
        u16x4 v1 = *(const u16x4*)(xr + 4);
        u16x4 v2 = *(const u16x4*)(xr + 8);
#pragma unroll
        for (int j = 0; j < 4; ++j) { xv[j] = b2f(v0[j]); xv[4 + j] = b2f(v1[j]); xv[8 + j] = b2f(v2[j]); }
        float p[13] = {};
        int d0 = lane * 12;
#pragma unroll
        for (int dd = 0; dd < 12; ++dd) {
            float xvv = xv[dd];
#pragma unroll
            for (int o = 0; o < 12; ++o) p[o] += xvv * hw[d0 + dd][o];
            p[12] += xvv * hw[d0 + dd][12];
        }
#pragma unroll
        for (int o = 0; o < 13; ++o) red[wave][lane][o] = p[o];
        __syncthreads();
        if (lane < 13) {
            float s = 0.f;
            for (int i = 0; i < 64; ++i) s += red[wave][i][lane];
            if (lane < 12) {
                int b = row >> 8, sidx = row & 255;
                float v = (s + head_b[lane]) * scalef[b * 12 + lane];
                int c = lane >> 2, py = (lane >> 1) & 1, px = lane & 1;
                int gy = sidx >> 4, gxx = sidx & 15;
                out[(((size_t)b * 3 + c) * 32 + 2 * gy + py) * 32 + 2 * gxx + px] = v;
            } else {
                rowlam[row] = s;
            }
        }
        __syncthreads();
    }
}

__global__ __launch_bounds__(256) void lpred_kernel(const float* __restrict__ rowlam,
                                                    const float* __restrict__ lam_b,
                                                    float* __restrict__ out) {
    int b = blockIdx.x, t = threadIdx.x;
    __shared__ float red[256];
    red[t] = rowlam[b * 256 + t];
    __syncthreads();
    for (int s2 = 128; s2 > 0; s2 >>= 1) { if (t < s2) red[t] += red[t + s2]; __syncthreads(); }
    if (t == 0) out[196608 + b] = red[0] / 256.0f + lam_b[0];
}

// ---------------------------------------------------------------------------
extern "C" void kernel_launch(void* const* d_in, const int* in_sizes, int n_in,
                              void* d_out, int out_size, void* d_ws, size_t ws_size,
                              hipStream_t stream) {
    const float* z_t     = (const float*)d_in[0];
    const float* logsnr  = (const float*)d_in[1];
    const float* qkv_w   = (const float*)d_in[2];
    const float* out_w   = (const float*)d_in[3];
    const float* gate_w  = (const float*)d_in[4];
    const float* gate_b  = (const float*)d_in[5];
    const float* mlpg_w  = (const float*)d_in[6];
    const float* mlpg_b  = (const float*)d_in[7];
    const float* mlpo_w  = (const float*)d_in[8];
    const float* mlpo_b  = (const float*)d_in[9];
    const float* hh_vs   = (const float*)d_in[10];
    const float* patch_w = (const float*)d_in[11];
    const float* patch_b = (const float*)d_in[12];
    const float* head_w  = (const float*)d_in[13];
    const float* head_b  = (const float*)d_in[14];
    const float* sd1_w   = (const float*)d_in[15];
    const float* sd1_b   = (const float*)d_in[16];
    const float* sd2_w   = (const float*)d_in[17];
    const float* sd2_b   = (const float*)d_in[18];
    const float* lam_w   = (const float*)d_in[19];
    const float* lam_b   = (const float*)d_in[20];

    char* wsb = (char*)d_ws;
    float* spins  = (float*)(wsb + B_SPINS);
    float* scalef = (float*)(wsb + B_SCALEF);
    float* qt     = (float*)(wsb + B_QT);
    float* cosb   = (float*)(wsb + B_COS);
    float* sinb   = (float*)(wsb + B_SIN);
    float* Gm     = (float*)(wsb + B_G);
    float* Tm     = (float*)(wsb + B_T);
    float* Am     = (float*)(wsb + B_AWY);
    float* rowlam = (float*)(wsb + B_ROWLAM);
    float* x      = (float*)(wsb + B_X);
    unsigned short* h      = (unsigned short*)(wsb + B_H);
    unsigned short* weff_t = (unsigned short*)(wsb + B_WEFFT);
    unsigned short* outw_t = (unsigned short*)(wsb + B_OUTWT);
    unsigned short* mlpg_t = (unsigned short*)(wsb + B_MLPGT);
    unsigned short* mlpo_t = (unsigned short*)(wsb + B_MLPOT);
    unsigned short* w2_t   = (unsigned short*)(wsb + B_W2T);
    unsigned short* arena  = (unsigned short*)(wsb + B_ARENA);
    unsigned short* qbuf = arena;
    unsigned short* kbuf = arena + ARENA_K;
    unsigned short* vtbuf = arena + 2 * ARENA_K;
    unsigned short* attnb = arena + 3 * ARENA_K;
    unsigned short* hidden = arena;
    float* out = (float*)d_out;

    // ---- setup ----
    spins_kernel<<<1, 64, 0, stream>>>(logsnr, spins);
    rope_table_kernel<<<256, 192, 0, stream>>>(cosb, sinb);
    hh_gram_kernel<<<8, 256, 0, stream>>>(hh_vs, Gm);
    hh_t_kernel<<<8, 128, 0, stream>>>(Gm, Tm);
    hh_a_kernel<<<8, 256, 0, stream>>>(Tm, hh_vs, Am);
    hh_p_kernel<<<8, 256, 0, stream>>>(hh_vs, Am, qt);
    fold_bf16t<<<dim3(3, 12, 64), 256, 0, stream>>>(qkv_w, qt, weff_t);
    transpose_bf16_kernel<<<dim3(24, 24, 8), 256, 0, stream>>>(qkv_w + 1536, 2304,
        (size_t)768 * 2304, weff_t + (size_t)1536 * 768, 768, (size_t)2304 * 768);
    transpose_bf16_kernel<<<dim3(24, 24, 8), 256, 0, stream>>>(out_w, 768,
        (size_t)768 * 768, outw_t, 768, (size_t)768 * 768);
    w2_bf16t<<<dim3(12, 12, 8), 256, 0, stream>>>(out_w, gate_w, w2_t);
    transpose_bf16_kernel<<<dim3(192, 24, 8), 256, 0, stream>>>(mlpg_w, 6144,
        (size_t)768 * 6144, mlpg_t, 768, (size_t)6144 * 768);
    transpose_bf16_kernel<<<dim3(24, 96, 8), 256, 0, stream>>>(mlpo_w, 768,
        (size_t)3072 * 768, mlpo_t, 3072, (size_t)768 * 3072);
    patch_embed_kernel<<<M_TOK, 256, 0, stream>>>(z_t, spins, patch_w, patch_b, x);

    for (int l = 0; l < Ll; ++l) {
        int glob = ((l + 1) % 4 == 0) ? 1 : 0;
        rmsnorm_kernel<<<4096, 256, 0, stream>>>(x, h);
        gemm_mfma<1><<<dim3(18, 128), 256, 0, stream>>>(h, 768,
            weff_t + (size_t)l * 2304 * 768, 768, arena, 0, 768, nullptr, nullptr, nullptr, 3);
        attn_mfma_kernel<<<dim3(2, 4, 64), 512, 0, stream>>>(qbuf, kbuf, vtbuf, attnb,
            cosb, sinb, glob);
        gemm_projgate<<<dim3(12, 64), 512, 0, stream>>>(attnb,
            outw_t + (size_t)l * 768 * 768, w2_t + (size_t)l * 768 * 768,
            gate_b + (size_t)l * 768, x, 3);
        rmsnorm_kernel<<<4096, 256, 0, stream>>>(x, h);
        gemm_mlp_fused<<<dim3(48, 64), 512, 0, stream>>>(h,
            mlpg_t + (size_t)l * 6144 * 768, hidden, mlpg_b + (size_t)l * 6144, 4);
        gemm_mfma<4><<<dim3(6, 128), 256, 0, stream>>>(hidden, 3072,
            mlpo_t + (size_t)l * 768 * 3072, 3072, nullptr, 768, 3072,
            mlpo_b + (size_t)l * 768, x, nullptr, 6);
    }

    rmsnorm_kernel<<<4096, 256, 0, stream>>>(x, h);
    scalef_kernel<<<64, 768, 0, stream>>>(spins, sd1_w, sd1_b, sd2_w, sd2_b, scalef);
    head_kernel<<<256, 256, 0, stream>>>(h, head_w, head_b, scalef, lam_w, out, rowlam);
    lpred_kernel<<<64, 256, 0, stream>>>(rowlam, lam_b, out);
}